// Round 5
// baseline (199.229 us; speedup 1.0000x reference)
//
#include <hip/hip_runtime.h>

#define B_ 8
#define C_ 256
#define N_ 2048
#define D_ 256
#define KKEEP 1843      // round(2048 * 0.9)
#define LEAKY 0.01f
#define EPS 1e-5f
#define NSTAT 1024

using short8  = __attribute__((ext_vector_type(8))) short;
using ushort8 = __attribute__((ext_vector_type(8))) unsigned short;
using ushort4v = __attribute__((ext_vector_type(4))) unsigned short;
using f32x4   = __attribute__((ext_vector_type(4))) float;

__device__ inline unsigned short f2bf(float x) {          // RNE f32->bf16
  unsigned u = __float_as_uint(x);
  u += 0x7fffu + ((u >> 16) & 1u);
  return (unsigned short)(u >> 16);
}
__device__ inline float bf2f(unsigned short u) { return __uint_as_float(((unsigned)u) << 16); }

// ---------- transpose + cast: src (rows x cols) fp32 -> dst (cols x rows) bf16
__global__ __launch_bounds__(256) void k_transpose_cast(const float* __restrict__ src,
                                                        unsigned short* __restrict__ dst,
                                                        int rows, int cols,
                                                        size_t srcBatch, size_t dstBatch) {
  __shared__ float tile[32][33];
  int b = blockIdx.z;
  src += (size_t)b * srcBatch;
  dst += (size_t)b * dstBatch;
  int i0 = blockIdx.y * 32;   // src row (c)
  int j0 = blockIdx.x * 32;   // src col (n)
  int t = threadIdx.x;
  int tc = t & 31, tr = t >> 5;
#pragma unroll
  for (int k = 0; k < 4; ++k)
    tile[tr + k * 8][tc] = src[(size_t)(i0 + tr + k * 8) * cols + j0 + tc];
  __syncthreads();
  int r2 = t >> 3, q = t & 7;                 // write row j0+r2, 4 consecutive c
  ushort4v v;
#pragma unroll
  for (int l = 0; l < 4; ++l) v[l] = f2bf(tile[q * 4 + l][r2]);
  *(ushort4v*)&dst[(size_t)(j0 + r2) * rows + i0 + q * 4] = v;
}

// ---------- NT MFMA GEMM: C[i][j] = sum_k A[i][k] * Bt[j][k]
// A: M x K_ bf16 row-major; Bt: cols x K_ bf16 row-major; tile 128 x BN.
// NSPLIT>1: blockIdx.z = b*NSPLIT + s, block covers K chunk [s*K_/NSPLIT, ...).
template<int K_, int NSPLIT, int BN, bool OUT_BF16, bool DO_LEAKY>
__global__ __launch_bounds__(256) void k_gemm(const short* __restrict__ A,
                                              const short* __restrict__ Bt,
                                              void* __restrict__ Cout,
                                              size_t aStride, size_t bStride, size_t cStride,
                                              size_t sStride, int ldc) {
  constexpr int FI = (BN == 128) ? 4 : 2;   // 16-row fragments per wave (M dir)
  constexpr int KC = K_ / NSPLIT;           // K elements this block reduces
  __shared__ short As[128][44];   // 88B row stride: starts spread over 16 banks
  __shared__ short Bs[BN][44];
  int zz = blockIdx.z;
  int b = zz / NSPLIT, s = zz % NSPLIT;
  A += (size_t)b * aStride + (size_t)s * KC;
  Bt += (size_t)b * bStride + (size_t)s * KC;
  int bi = blockIdx.y * 128;
  int bj = blockIdx.x * BN;
  int t = threadIdx.x;
  int lane = t & 63, wid = t >> 6;
  int wr, wc;
  if constexpr (BN == 128) { wr = (wid >> 1) * 64; wc = (wid & 1) * 64; }
  else                     { wr = wid * 32;        wc = 0; }

  int r0 = t >> 2, k0 = (t & 3) * 8;
  int r1 = r0 + 64;
  const short* aP0 = A + (size_t)(bi + r0) * K_ + k0;   // row stride = full K_
  const short* aP1 = A + (size_t)(bi + r1) * K_ + k0;
  const short* bP0 = Bt + (size_t)(bj + r0) * K_ + k0;
  const short* bP1 = Bt + (size_t)(bj + (BN == 128 ? r1 : r0)) * K_ + k0;

  short8 a0 = *(const short8*)aP0;
  short8 a1 = *(const short8*)aP1;
  short8 b0 = *(const short8*)bP0;
  short8 b1;
  if constexpr (BN == 128) b1 = *(const short8*)bP1;

  f32x4 acc[FI][4];
  f32x4 z = {0.f, 0.f, 0.f, 0.f};
#pragma unroll
  for (int i = 0; i < FI; ++i)
#pragma unroll
    for (int j = 0; j < 4; ++j) acc[i][j] = z;

  int fr = lane & 15;
  int ks = (lane >> 4) * 8;

  for (int c0 = 0; c0 < KC; c0 += 32) {
    __syncthreads();
    *(short8*)&As[r0][k0] = a0;
    *(short8*)&As[r1][k0] = a1;
    *(short8*)&Bs[r0][k0] = b0;
    if constexpr (BN == 128) *(short8*)&Bs[r1][k0] = b1;
    __syncthreads();
    if (c0 + 32 < KC) {   // prefetch next K-slab while computing this one
      a0 = *(const short8*)(aP0 + c0 + 32);
      a1 = *(const short8*)(aP1 + c0 + 32);
      b0 = *(const short8*)(bP0 + c0 + 32);
      if constexpr (BN == 128) b1 = *(const short8*)(bP1 + c0 + 32);
    }
    short8 af[FI], bf[4];
#pragma unroll
    for (int f = 0; f < FI; ++f) af[f] = *(const short8*)&As[wr + f * 16 + fr][ks];
#pragma unroll
    for (int f = 0; f < 4; ++f)  bf[f] = *(const short8*)&Bs[wc + f * 16 + fr][ks];
#pragma unroll
    for (int fi = 0; fi < FI; ++fi)
#pragma unroll
      for (int fj = 0; fj < 4; ++fj)
        acc[fi][fj] = __builtin_amdgcn_mfma_f32_16x16x32_bf16(af[fi], bf[fj], acc[fi][fj], 0, 0, 0);
  }

  // epilogue: C/D layout: col = lane&15, row = (lane>>4)*4 + reg
  int orow = (lane >> 4) * 4;
  int ocol = lane & 15;
#pragma unroll
  for (int fi = 0; fi < FI; ++fi)
#pragma unroll
    for (int fj = 0; fj < 4; ++fj)
#pragma unroll
      for (int r = 0; r < 4; ++r) {
        float v = acc[fi][fj][r];
        if (DO_LEAKY) v = (v >= 0.f) ? v : LEAKY * v;
        size_t idx = (size_t)b * cStride + (size_t)s * sStride +
                     (size_t)(bi + wr + fi * 16 + orow + r) * ldc +
                     (size_t)(bj + wc + fj * 16 + ocol);
        if (OUT_BF16) ((unsigned short*)Cout)[idx] = f2bf(v);
        else          ((float*)Cout)[idx] = v;
      }
}

// ---------- softmax + exact(bf16-granularity) top-k threshold + mask, one WAVE per row
__global__ __launch_bounds__(256) void k_softmax_topk(unsigned short* __restrict__ S) {
  int t = threadIdx.x;
  int lane = t & 63, wv = t >> 6;
  size_t row = (size_t)blockIdx.x * 4 + wv;
  unsigned short* sr = S + row * N_;

  float e[32];
#pragma unroll
  for (int i = 0; i < 4; ++i) {
    ushort8 raw = *(const ushort8*)(sr + ((size_t)(i * 64 + lane)) * 8);
#pragma unroll
    for (int j = 0; j < 8; ++j) e[i * 8 + j] = bf2f(raw[j]);
  }

  float lm = e[0];
#pragma unroll
  for (int j = 1; j < 32; ++j) lm = fmaxf(lm, e[j]);
#pragma unroll
  for (int m = 1; m <= 16; m <<= 1) lm = fmaxf(lm, __shfl_xor(lm, m));
  lm = fmaxf(__shfl(lm, 0), __shfl(lm, 32));

  float ls = 0.f;
#pragma unroll
  for (int j = 0; j < 32; ++j) { e[j] = __expf(e[j] - lm); ls += e[j]; }
#pragma unroll
  for (int m = 1; m <= 16; m <<= 1) ls += __shfl_xor(ls, m);
  ls = __shfl(ls, 0) + __shfl(ls, 32);
  float inv = 1.0f / ls;

  unsigned kp[16], vo[16];
#pragma unroll
  for (int q = 0; q < 16; ++q)
    kp[q] = (unsigned)f2bf(e[q]) | ((unsigned)f2bf(e[q + 16]) << 16);
#pragma unroll
  for (int q = 0; q < 16; ++q)
    vo[q] = (unsigned)f2bf(e[2 * q] * inv) | ((unsigned)f2bf(e[2 * q + 1] * inv) << 16);

  unsigned tp[16];
#pragma unroll
  for (int q = 0; q < 16; ++q) tp[q] = kp[q];
#pragma unroll
  for (int sI = 0; sI < 4; ++sI) {
    const int s = 8 >> sI;
    const unsigned msk = (s == 8) ? 0x00FF00FFu : (s == 4) ? 0x0F0F0F0Fu
                       : (s == 2) ? 0x33333333u : 0x55555555u;
#pragma unroll
    for (int k = 0; k < 16; ++k) {
      if ((k & s) == 0) {
        unsigned tt = ((tp[k] >> s) ^ tp[k + s]) & msk;
        tp[k + s] ^= tt;
        tp[k]     ^= tt << s;
      }
    }
  }

  unsigned alive = 0xFFFFFFFFu, prefix = 0u;
  int need = KKEEP;
#pragma unroll
  for (int b = 12; b >= 0; b -= 2) {
    unsigned p1 = tp[b + 1], p0 = tp[b];
    unsigned hi = alive & p1;
    unsigned m3 = hi & p0, m2 = hi & ~p0, m1v = (alive & ~p1) & p0;
    unsigned packed = (unsigned)__popc(m3) | ((unsigned)__popc(m2) << 11) |
                      ((unsigned)__popc(m1v) << 22);
#pragma unroll
    for (int m = 1; m <= 16; m <<= 1) packed += __shfl_xor(packed, m);
    unsigned v0 = __shfl(packed, 0), v32 = __shfl(packed, 32);
    int C3 = (int)((v0 & 0x7FFu) + (v32 & 0x7FFu));
    int C2 = (int)(((v0 >> 11) & 0x7FFu) + ((v32 >> 11) & 0x7FFu));
    int C1 = (int)(((v0 >> 22) & 0x7FFu) + ((v32 >> 22) & 0x7FFu));
    int cum2 = C3 + C2, cum1 = cum2 + C1;
    if (C3 >= need)        { alive = m3;  prefix |= 3u << b; }
    else if (cum2 >= need) { alive = m2;  prefix |= 2u << b; need -= C3; }
    else if (cum1 >= need) { alive = m1v; prefix |= 1u << b; need -= cum2; }
    else                   { alive ^= (m3 | m2 | m1v);       need -= cum1; }
  }

#pragma unroll
  for (int i = 0; i < 4; ++i) {
    ushort8 o;
#pragma unroll
    for (int j = 0; j < 8; ++j) {
      int idx = i * 8 + j;
      unsigned key = (kp[idx & 15] >> ((idx >> 4) * 16)) & 0xFFFFu;
      unsigned val = (vo[idx >> 1] >> ((idx & 1) * 16)) & 0xFFFFu;
      o[j] = (key >= prefix) ? (unsigned short)val : (unsigned short)0;
    }
    *(ushort8*)(sr + ((size_t)(i * 64 + lane)) * 8) = o;
  }
}

// ---------- fused split-K reduce + leaky + BN partial stats
__global__ __launch_bounds__(256) void k_stats(const float* __restrict__ part,
                                               float* __restrict__ pre,
                                               float* __restrict__ ps,
                                               float* __restrict__ pss) {
  int t = threadIdx.x;
  int g = blockIdx.x;                        // NSTAT blocks
  const int ROWS = (B_ * N_) / NSTAT;        // 16 rows each
  const size_t SS = (size_t)B_ * N_ * D_;
  size_t base = (size_t)g * ROWS * D_;
  float s = 0.f, ss = 0.f;
  for (int r = 0; r < ROWS; ++r) {
    size_t idx = base + (size_t)r * D_ + t;
    float v = part[idx] + part[idx + SS] + part[idx + 2 * SS] + part[idx + 3 * SS];
    v = (v >= 0.f) ? v : LEAKY * v;
    pre[idx] = v;
    s += v;
    ss = fmaf(v, v, ss);
  }
  ps[(size_t)g * 256 + t] = s;
  pss[(size_t)g * 256 + t] = ss;
}

__global__ void k_final(const float* __restrict__ ps, const float* __restrict__ pss,
                        const float* __restrict__ bnw, const float* __restrict__ bnb,
                        float* __restrict__ scale, float* __restrict__ shift) {
  int t = threadIdx.x;  // 256
  float s = 0.f, ss = 0.f;
  for (int g = 0; g < NSTAT; ++g) {
    s += ps[(size_t)g * 256 + t];
    ss += pss[(size_t)g * 256 + t];
  }
  const float invN = 1.0f / (B_ * N_);
  float mean = s * invN;
  float var = fmaf(-mean, mean, ss * invN);
  float istd = rsqrtf(var + EPS);
  float sc = istd * bnw[t];
  scale[t] = sc;
  shift[t] = fmaf(-mean, sc, bnb[t]);
}

// ---------- normalize + transpose (b,n,d) -> (b,d,n)
__global__ __launch_bounds__(256) void k_out(const float* __restrict__ pre,
                                             const float* __restrict__ scale,
                                             const float* __restrict__ shift,
                                             float* __restrict__ out) {
  __shared__ float tile[32][33];
  int blk = blockIdx.x;
  int d0 = (blk % (D_ / 32)) * 32;
  int n0 = ((blk / (D_ / 32)) % (N_ / 32)) * 32;
  int b = blk / ((D_ / 32) * (N_ / 32));
  int tc = threadIdx.x & 31;
  int tr = threadIdx.x >> 5;
  const float* pb = pre + ((size_t)b * N_ + n0) * D_ + d0;
#pragma unroll
  for (int i = 0; i < 4; ++i) {
    int r = tr + i * 8;
    tile[r][tc] = pb[(size_t)r * D_ + tc];
  }
  __syncthreads();
  float* ob = out + ((size_t)b * D_ + d0) * N_ + n0;
#pragma unroll
  for (int i = 0; i < 4; ++i) {
    int r = tr + i * 8;
    float vv = tile[tc][r];
    ob[(size_t)r * N_ + tc] = fmaf(vv, scale[d0 + r], shift[d0 + r]);
  }
}

extern "C" void kernel_launch(void* const* d_in, const int* in_sizes, int n_in,
                              void* d_out, int out_size, void* d_ws, size_t ws_size,
                              hipStream_t stream) {
  const float* x = (const float*)d_in[0];
  const float* W = (const float*)d_in[1];
  const float* bnw = (const float*)d_in[2];
  const float* bnb = (const float*)d_in[3];
  float* out = (float*)d_out;

  char* w = (char*)d_ws;
  short* xt = (short*)w;            w += (size_t)B_ * N_ * C_ * 2;   // (b,n,c) bf16   8.4 MB
  short* wt = (short*)w;            w += (size_t)D_ * C_ * 2;        // (d,c) bf16
  short* supT = (short*)w;          w += (size_t)B_ * D_ * N_ * 2;   // (b,d,m) bf16   8.4 MB
  short* S = (short*)w;             w += (size_t)B_ * N_ * N_ * 2;   // (b,n,m) bf16   67 MB
  float* part = (float*)w;          w += (size_t)4 * B_ * N_ * D_ * 4; // split-K f32  67 MB
  float* ps = (float*)w;            w += (size_t)NSTAT * 256 * 4;
  float* pss = (float*)w;           w += (size_t)NSTAT * 256 * 4;
  float* scale = (float*)w;         w += D_ * 4;
  float* shift = (float*)w;         w += D_ * 4;
  float* pre = (float*)S;           // aliases S: S is dead once PV finishes

  // 1. layout prep
  k_transpose_cast<<<dim3(N_ / 32, C_ / 32, B_), 256, 0, stream>>>(
      x, (unsigned short*)xt, C_, N_, (size_t)C_ * N_, (size_t)N_ * C_);
  k_transpose_cast<<<dim3(D_ / 32, C_ / 32, 1), 256, 0, stream>>>(
      W, (unsigned short*)wt, C_, D_, 0, 0);

  // 2. supT(d,m) = wt . xt^T
  k_gemm<C_, 1, 64, true, false><<<dim3(N_ / 64, 2, B_), 256, 0, stream>>>(
      wt, xt, supT, 0, (size_t)N_ * C_, (size_t)D_ * N_, 0, N_);

  // 3. S(n,m) = xt . xt^T
  k_gemm<C_, 1, 128, true, false><<<dim3(16, 16, B_), 256, 0, stream>>>(
      xt, xt, S, (size_t)N_ * C_, (size_t)N_ * C_, (size_t)N_ * N_, 0, N_);

  // 4. softmax + topk mask (in place), one wave per row
  k_softmax_topk<<<B_ * N_ / 4, 256, 0, stream>>>((unsigned short*)S);

  // 5. part[s](n,d) = P . supT^T over K-chunk s (split-K=4, 2048 wg)
  k_gemm<N_, 4, 64, false, false><<<dim3(D_ / 64, N_ / 128, B_ * 4), 256, 0, stream>>>(
      S, supT, part, (size_t)N_ * N_, (size_t)D_ * N_, (size_t)N_ * D_,
      (size_t)B_ * N_ * D_, D_);

  // 6. reduce splits + leaky + BN stats, then finalize + output
  k_stats<<<NSTAT, 256, 0, stream>>>(part, pre, ps, pss);
  k_final<<<1, 256, 0, stream>>>(ps, pss, bnw, bnb, scale, shift);
  k_out<<<B_ * (N_ / 32) * (D_ / 32), 256, 0, stream>>>(pre, scale, shift, out);
}

// Round 6
// 131.866 us; speedup vs baseline: 1.5108x; 1.5108x over previous
//
#include <hip/hip_runtime.h>

#define B_ 8
#define C_ 256
#define N_ 2048
#define D_ 256
#define KKEEP 1843      // round(2048 * 0.9)
#define LEAKY 0.01f
#define EPS 1e-5f

using short8  = __attribute__((ext_vector_type(8))) short;
using ushort8 = __attribute__((ext_vector_type(8))) unsigned short;
using ushort4v = __attribute__((ext_vector_type(4))) unsigned short;
using f32x4   = __attribute__((ext_vector_type(4))) float;

__device__ inline unsigned short f2bf(float x) {          // RNE f32->bf16
  unsigned u = __float_as_uint(x);
  u += 0x7fffu + ((u >> 16) & 1u);
  return (unsigned short)(u >> 16);
}
__device__ inline float bf2f(unsigned short u) { return __uint_as_float(((unsigned)u) << 16); }

// ---------- transpose + cast: src (rows x cols) fp32 -> dst (cols x rows) bf16
__global__ __launch_bounds__(256) void k_transpose_cast(const float* __restrict__ src,
                                                        unsigned short* __restrict__ dst,
                                                        int rows, int cols,
                                                        size_t srcBatch, size_t dstBatch) {
  __shared__ float tile[32][33];
  int b = blockIdx.z;
  src += (size_t)b * srcBatch;
  dst += (size_t)b * dstBatch;
  int i0 = blockIdx.y * 32;   // src row (c)
  int j0 = blockIdx.x * 32;   // src col (n)
  int t = threadIdx.x;
  int tc = t & 31, tr = t >> 5;
#pragma unroll
  for (int k = 0; k < 4; ++k)
    tile[tr + k * 8][tc] = src[(size_t)(i0 + tr + k * 8) * cols + j0 + tc];
  __syncthreads();
  int r2 = t >> 3, q = t & 7;                 // write row j0+r2, 4 consecutive c
  ushort4v v;
#pragma unroll
  for (int l = 0; l < 4; ++l) v[l] = f2bf(tile[q * 4 + l][r2]);
  *(ushort4v*)&dst[(size_t)(j0 + r2) * rows + i0 + q * 4] = v;
}

// ---------- NT MFMA GEMM: C[i][j] = sum_k A[i][k] * Bt[j][k]
// A: M x K_ bf16 row-major; Bt: cols x K_ bf16 row-major; tile 128 x BN.
// SWZ: 1-D grid, b = lin&7 pins batch -> XCD (round-robin dispatch), so per-batch
// operand panels are fetched by exactly one XCD's L2.
template<int K_, int BN, bool OUT_BF16, bool DO_LEAKY, bool SWZ>
__global__ __launch_bounds__(256) void k_gemm(const short* __restrict__ A,
                                              const short* __restrict__ Bt,
                                              void* __restrict__ Cout,
                                              size_t aStride, size_t bStride, size_t cStride,
                                              int ldc, int nx) {
  constexpr int FI = (BN == 128) ? 4 : 2;   // 16-row fragments per wave (M dir)
  __shared__ short As[128][44];   // 88B row stride: fragment starts spread over 16 banks
  __shared__ short Bs[BN][44];
  int b, bxi, byi;
  if constexpr (SWZ) {
    int lin = blockIdx.x;
    b = lin & 7;                 // XCD id == batch
    int rest = lin >> 3;
    bxi = rest % nx;             // x fast: consecutive same-XCD blocks share A-panel
    byi = rest / nx;
  } else {
    b = blockIdx.z; bxi = blockIdx.x; byi = blockIdx.y;
  }
  A += (size_t)b * aStride;
  Bt += (size_t)b * bStride;
  int bi = byi * 128;
  int bj = bxi * BN;
  int t = threadIdx.x;
  int lane = t & 63, wid = t >> 6;
  int wr, wc;
  if constexpr (BN == 128) { wr = (wid >> 1) * 64; wc = (wid & 1) * 64; }
  else                     { wr = wid * 32;        wc = 0; }

  int r0 = t >> 2, k0 = (t & 3) * 8;
  int r1 = r0 + 64;
  const short* aP0 = A + (size_t)(bi + r0) * K_ + k0;
  const short* aP1 = A + (size_t)(bi + r1) * K_ + k0;
  const short* bP0 = Bt + (size_t)(bj + r0) * K_ + k0;
  const short* bP1 = Bt + (size_t)(bj + (BN == 128 ? r1 : r0)) * K_ + k0;

  short8 a0 = *(const short8*)aP0;
  short8 a1 = *(const short8*)aP1;
  short8 b0 = *(const short8*)bP0;
  short8 b1;
  if constexpr (BN == 128) b1 = *(const short8*)bP1;

  f32x4 acc[FI][4];
  f32x4 z = {0.f, 0.f, 0.f, 0.f};
#pragma unroll
  for (int i = 0; i < FI; ++i)
#pragma unroll
    for (int j = 0; j < 4; ++j) acc[i][j] = z;

  int fr = lane & 15;
  int ks = (lane >> 4) * 8;

  for (int c0 = 0; c0 < K_; c0 += 32) {
    __syncthreads();
    *(short8*)&As[r0][k0] = a0;
    *(short8*)&As[r1][k0] = a1;
    *(short8*)&Bs[r0][k0] = b0;
    if constexpr (BN == 128) *(short8*)&Bs[r1][k0] = b1;
    __syncthreads();
    if (c0 + 32 < K_) {   // prefetch next K-slab while computing this one
      a0 = *(const short8*)(aP0 + c0 + 32);
      a1 = *(const short8*)(aP1 + c0 + 32);
      b0 = *(const short8*)(bP0 + c0 + 32);
      if constexpr (BN == 128) b1 = *(const short8*)(bP1 + c0 + 32);
    }
    short8 af[FI], bf[4];
#pragma unroll
    for (int f = 0; f < FI; ++f) af[f] = *(const short8*)&As[wr + f * 16 + fr][ks];
#pragma unroll
    for (int f = 0; f < 4; ++f)  bf[f] = *(const short8*)&Bs[wc + f * 16 + fr][ks];
#pragma unroll
    for (int fi = 0; fi < FI; ++fi)
#pragma unroll
      for (int fj = 0; fj < 4; ++fj)
        acc[fi][fj] = __builtin_amdgcn_mfma_f32_16x16x32_bf16(af[fi], bf[fj], acc[fi][fj], 0, 0, 0);
  }

  // epilogue: C/D layout: col = lane&15, row = (lane>>4)*4 + reg
  int orow = (lane >> 4) * 4;
  int ocol = lane & 15;
#pragma unroll
  for (int fi = 0; fi < FI; ++fi)
#pragma unroll
    for (int fj = 0; fj < 4; ++fj)
#pragma unroll
      for (int r = 0; r < 4; ++r) {
        float v = acc[fi][fj][r];
        if (DO_LEAKY) v = (v >= 0.f) ? v : LEAKY * v;
        size_t idx = (size_t)b * cStride +
                     (size_t)(bi + wr + fi * 16 + orow + r) * ldc +
                     (size_t)(bj + wc + fj * 16 + ocol);
        if (OUT_BF16) ((unsigned short*)Cout)[idx] = f2bf(v);
        else          ((float*)Cout)[idx] = v;
      }
}

// ---------- softmax + exact(bf16-granularity) top-k threshold + mask, one WAVE per row
__global__ __launch_bounds__(256) void k_softmax_topk(unsigned short* __restrict__ S) {
  int t = threadIdx.x;
  int lane = t & 63, wv = t >> 6;
  size_t row = (size_t)blockIdx.x * 4 + wv;
  unsigned short* sr = S + row * N_;

  float e[32];
#pragma unroll
  for (int i = 0; i < 4; ++i) {
    ushort8 raw = *(const ushort8*)(sr + ((size_t)(i * 64 + lane)) * 8);
#pragma unroll
    for (int j = 0; j < 8; ++j) e[i * 8 + j] = bf2f(raw[j]);
  }

  float lm = e[0];
#pragma unroll
  for (int j = 1; j < 32; ++j) lm = fmaxf(lm, e[j]);
#pragma unroll
  for (int m = 1; m <= 16; m <<= 1) lm = fmaxf(lm, __shfl_xor(lm, m));
  lm = fmaxf(__shfl(lm, 0), __shfl(lm, 32));

  float ls = 0.f;
#pragma unroll
  for (int j = 0; j < 32; ++j) { e[j] = __expf(e[j] - lm); ls += e[j]; }
#pragma unroll
  for (int m = 1; m <= 16; m <<= 1) ls += __shfl_xor(ls, m);
  ls = __shfl(ls, 0) + __shfl(ls, 32);
  float inv = 1.0f / ls;

  unsigned kp[16], vo[16];
#pragma unroll
  for (int q = 0; q < 16; ++q)
    kp[q] = (unsigned)f2bf(e[q]) | ((unsigned)f2bf(e[q + 16]) << 16);
#pragma unroll
  for (int q = 0; q < 16; ++q)
    vo[q] = (unsigned)f2bf(e[2 * q] * inv) | ((unsigned)f2bf(e[2 * q + 1] * inv) << 16);

  unsigned tp[16];
#pragma unroll
  for (int q = 0; q < 16; ++q) tp[q] = kp[q];
#pragma unroll
  for (int sI = 0; sI < 4; ++sI) {
    const int s = 8 >> sI;
    const unsigned msk = (s == 8) ? 0x00FF00FFu : (s == 4) ? 0x0F0F0F0Fu
                       : (s == 2) ? 0x33333333u : 0x55555555u;
#pragma unroll
    for (int k = 0; k < 16; ++k) {
      if ((k & s) == 0) {
        unsigned tt = ((tp[k] >> s) ^ tp[k + s]) & msk;
        tp[k + s] ^= tt;
        tp[k]     ^= tt << s;
      }
    }
  }

  unsigned alive = 0xFFFFFFFFu, prefix = 0u;
  int need = KKEEP;
#pragma unroll
  for (int b = 12; b >= 0; b -= 2) {
    unsigned p1 = tp[b + 1], p0 = tp[b];
    unsigned hi = alive & p1;
    unsigned m3 = hi & p0, m2 = hi & ~p0, m1v = (alive & ~p1) & p0;
    unsigned packed = (unsigned)__popc(m3) | ((unsigned)__popc(m2) << 11) |
                      ((unsigned)__popc(m1v) << 22);
#pragma unroll
    for (int m = 1; m <= 16; m <<= 1) packed += __shfl_xor(packed, m);
    unsigned v0 = __shfl(packed, 0), v32 = __shfl(packed, 32);
    int C3 = (int)((v0 & 0x7FFu) + (v32 & 0x7FFu));
    int C2 = (int)(((v0 >> 11) & 0x7FFu) + ((v32 >> 11) & 0x7FFu));
    int C1 = (int)(((v0 >> 22) & 0x7FFu) + ((v32 >> 22) & 0x7FFu));
    int cum2 = C3 + C2, cum1 = cum2 + C1;
    if (C3 >= need)        { alive = m3;  prefix |= 3u << b; }
    else if (cum2 >= need) { alive = m2;  prefix |= 2u << b; need -= C3; }
    else if (cum1 >= need) { alive = m1v; prefix |= 1u << b; need -= cum2; }
    else                   { alive ^= (m3 | m2 | m1v);       need -= cum1; }
  }

#pragma unroll
  for (int i = 0; i < 4; ++i) {
    ushort8 o;
#pragma unroll
    for (int j = 0; j < 8; ++j) {
      int idx = i * 8 + j;
      unsigned key = (kp[idx & 15] >> ((idx >> 4) * 16)) & 0xFFFFu;
      unsigned val = (vo[idx >> 1] >> ((idx & 1) * 16)) & 0xFFFFu;
      o[j] = (key >= prefix) ? (unsigned short)val : (unsigned short)0;
    }
    *(ushort8*)(sr + ((size_t)(i * 64 + lane)) * 8) = o;
  }
}

// ---------- BN statistics: per-block partials (no atomics)
__global__ __launch_bounds__(256) void k_stats(const float* __restrict__ pre,
                                               float* __restrict__ ps,
                                               float* __restrict__ pss) {
  int t = threadIdx.x;
  int g = blockIdx.x;                    // 256 blocks
  const int ROWS = (B_ * N_) / 256;      // 64 rows each
  const float* pb = pre + (size_t)g * ROWS * D_;
  float s = 0.f, ss = 0.f;
  for (int r = 0; r < ROWS; ++r) {
    float vv = pb[(size_t)r * D_ + t];
    s += vv;
    ss = fmaf(vv, vv, ss);
  }
  ps[g * 256 + t] = s;
  pss[g * 256 + t] = ss;
}

__global__ void k_final(const float* __restrict__ ps, const float* __restrict__ pss,
                        const float* __restrict__ bnw, const float* __restrict__ bnb,
                        float* __restrict__ scale, float* __restrict__ shift) {
  int t = threadIdx.x;  // 256
  float s = 0.f, ss = 0.f;
  for (int g = 0; g < 256; ++g) {
    s += ps[g * 256 + t];
    ss += pss[g * 256 + t];
  }
  const float invN = 1.0f / (B_ * N_);
  float mean = s * invN;
  float var = fmaf(-mean, mean, ss * invN);
  float istd = rsqrtf(var + EPS);
  float sc = istd * bnw[t];
  scale[t] = sc;
  shift[t] = fmaf(-mean, sc, bnb[t]);
}

// ---------- normalize + transpose (b,n,d) -> (b,d,n)
__global__ __launch_bounds__(256) void k_out(const float* __restrict__ pre,
                                             const float* __restrict__ scale,
                                             const float* __restrict__ shift,
                                             float* __restrict__ out) {
  __shared__ float tile[32][33];
  int blk = blockIdx.x;
  int d0 = (blk % (D_ / 32)) * 32;
  int n0 = ((blk / (D_ / 32)) % (N_ / 32)) * 32;
  int b = blk / ((D_ / 32) * (N_ / 32));
  int tc = threadIdx.x & 31;
  int tr = threadIdx.x >> 5;
  const float* pb = pre + ((size_t)b * N_ + n0) * D_ + d0;
#pragma unroll
  for (int i = 0; i < 4; ++i) {
    int r = tr + i * 8;
    tile[r][tc] = pb[(size_t)r * D_ + tc];
  }
  __syncthreads();
  float* ob = out + ((size_t)b * D_ + d0) * N_ + n0;
#pragma unroll
  for (int i = 0; i < 4; ++i) {
    int r = tr + i * 8;
    float vv = tile[tc][r];
    ob[(size_t)r * N_ + tc] = fmaf(vv, scale[d0 + r], shift[d0 + r]);
  }
}

extern "C" void kernel_launch(void* const* d_in, const int* in_sizes, int n_in,
                              void* d_out, int out_size, void* d_ws, size_t ws_size,
                              hipStream_t stream) {
  const float* x = (const float*)d_in[0];
  const float* W = (const float*)d_in[1];
  const float* bnw = (const float*)d_in[2];
  const float* bnb = (const float*)d_in[3];
  float* out = (float*)d_out;

  char* w = (char*)d_ws;
  short* xt = (short*)w;            w += (size_t)B_ * N_ * C_ * 2;   // (b,n,c) bf16
  short* wt = (short*)w;            w += (size_t)D_ * C_ * 2;        // (d,c) bf16
  short* supT = (short*)w;          w += (size_t)B_ * D_ * N_ * 2;   // (b,d,m) bf16
  short* S = (short*)w;             w += (size_t)B_ * N_ * N_ * 2;   // (b,n,m) bf16
  float* pre = (float*)w;           w += (size_t)B_ * N_ * D_ * 4;   // (b,n,d) f32
  float* ps = (float*)w;            w += 256 * 256 * 4;              // stat partials
  float* pss = (float*)w;           w += 256 * 256 * 4;
  float* scale = (float*)w;         w += D_ * 4;
  float* shift = (float*)w;         w += D_ * 4;

  // 1. layout prep
  k_transpose_cast<<<dim3(N_ / 32, C_ / 32, B_), 256, 0, stream>>>(
      x, (unsigned short*)xt, C_, N_, (size_t)C_ * N_, (size_t)N_ * C_);
  k_transpose_cast<<<dim3(D_ / 32, C_ / 32, 1), 256, 0, stream>>>(
      W, (unsigned short*)wt, C_, D_, 0, 0);

  // 2. supT(d,m) = wt . xt^T  (small; unswizzled)
  k_gemm<C_, 64, true, false, false><<<dim3(N_ / 64, 2, B_), 256, 0, stream>>>(
      wt, xt, supT, 0, (size_t)N_ * C_, (size_t)D_ * N_, N_, 0);

  // 3. S(n,m) = xt . xt^T  — batch->XCD pinned, 2048 blocks
  k_gemm<C_, 128, true, false, true><<<dim3(16 * 16 * B_, 1, 1), 256, 0, stream>>>(
      xt, xt, S, (size_t)N_ * C_, (size_t)N_ * C_, (size_t)N_ * N_, N_, 16);

  // 4. softmax + topk mask (in place), one wave per row
  k_softmax_topk<<<B_ * N_ / 4, 256, 0, stream>>>((unsigned short*)S);

  // 5. pre(n,d) = P . supT^T, leaky fused — batch->XCD pinned, 512 blocks
  k_gemm<N_, 64, false, true, true><<<dim3(4 * 16 * B_, 1, 1), 256, 0, stream>>>(
      S, supT, pre, (size_t)N_ * N_, (size_t)D_ * N_, (size_t)N_ * D_, D_, 4);

  // 6. BN stats + finalize + output
  k_stats<<<256, 256, 0, stream>>>(pre, ps, pss);
  k_final<<<1, 256, 0, stream>>>(ps, pss, bnw, bnb, scale, shift);
  k_out<<<B_ * (N_ / 32) * (D_ / 32), 256, 0, stream>>>(pre, scale, shift, out);
}